// Round 16
// baseline (354.362 us; speedup 1.0000x reference)
//
#include <hip/hip_runtime.h>
#include <hip/hip_bf16.h>
#include <math.h>
#include <stdint.h>

typedef __attribute__((ext_vector_type(8))) short s16x8;
typedef __attribute__((ext_vector_type(4))) float f32x4;
typedef __attribute__((ext_vector_type(4))) u_int32_t u32x4;
typedef unsigned int u32;
typedef unsigned short u16;

#define DEVINL __device__ __forceinline__
#define VMW0 asm volatile("s_waitcnt vmcnt(0)" ::: "memory")

DEVINL u16 f2bf(float f) {
    u32 b = __builtin_bit_cast(u32, f);
    u32 r = (b + 0x7fffu + ((b >> 16) & 1u)) >> 16;
    return (u16)r;
}

DEVINL float bf2f(u16 u) {
    u32 b = (u32)u << 16;
    return __builtin_bit_cast(float, b);
}

DEVINL float fexp2(float x) {
    float r;
    asm("v_exp_f32 %0, %1" : "=v"(r) : "v"(x));
    return r;
}

DEVINL float frcp(float x) {
    float r;
    asm("v_rcp_f32 %0, %1" : "=v"(r) : "v"(x));
    return r;
}

DEVINL u32 cvt_pk_bf16(float lo, float hi) {
    u32 r;
    asm("v_cvt_pk_bf16_f32 %0, %1, %2" : "=v"(r) : "v"(lo), "v"(hi));
    return r;
}

// fast GELU: tanh form, gelu(x) = x*u/(u+1), u = exp2(x*(c1 + c2*x^2))
DEVINL float fgelu(float v) {
    const float x2 = v * v;
    const float u = fexp2(v * __builtin_fmaf(0.10294310f, x2, 2.3022165f));
    return v * u * frcp(u + 1.0f);
}

DEVINL void gload_lds16(const void* g, const void* l) {
    __builtin_amdgcn_global_load_lds(
        (const __attribute__((address_space(1))) u32*)(uintptr_t)g,
        (__attribute__((address_space(3))) u32*)(uintptr_t)l, 16, 0, 0);
}

// ---------------- elementwise f32 -> bf16 ----------------
__global__ __launch_bounds__(256)
void cvt_bf16_kernel(const float* __restrict__ in, u16* __restrict__ out, int n4)
{
    int i = blockIdx.x * 256 + threadIdx.x;
    const int stride = gridDim.x * 256;
    for (; i < n4; i += stride) {
        float4 v = ((const float4*)in)[i];
        ushort4 o;
        o.x = f2bf(v.x); o.y = f2bf(v.y); o.z = f2bf(v.z); o.w = f2bf(v.w);
        ((ushort4*)out)[i] = o;
    }
}

// ------------- transpose + convert weights: src[R][C] f32 -> dst[C][R] bf16 -------------
__global__ __launch_bounds__(256)
void transpose_cvt(const float* __restrict__ src, u16* __restrict__ dst, int R, int C)
{
    __shared__ float tile[64][65];
    const int t = threadIdx.x;
    const int c0 = blockIdx.x * 64, r0 = blockIdx.y * 64;
    const int rr = t >> 6;   // 0..3
    const int cc = t & 63;
    #pragma unroll
    for (int i = 0; i < 16; ++i)
        tile[i * 4 + rr][cc] = src[(size_t)(r0 + i * 4 + rr) * C + c0 + cc];
    __syncthreads();
    #pragma unroll
    for (int i = 0; i < 16; ++i) {
        int orow = i * 4 + rr;           // source col
        dst[(size_t)(c0 + orow) * R + r0 + cc] = f2bf(tile[cc][orow]);
    }
}

// ------------- V transpose: qkv[B,T, 2048+h*64+d] bf16 -> vt[bh, d, sigma(t)] bf16 -------
// sigma: token cc stored at position matching the in-register packed-P virtual k-order
__global__ __launch_bounds__(256)
void vtrans_kernel(const u16* __restrict__ qkv, u16* __restrict__ vt)
{
    __shared__ u16 tile[64][68];
    const int t = threadIdx.x;
    const int st = blockIdx.x;       // T/64
    const int bh = blockIdx.y;       // B*H
    const int b = bh >> 4, h = bh & 15;
    const int s0 = st * 64;
    const int rr = t >> 6, cc = t & 63;
    const int sc = (cc & 32) | (((cc >> 2) & 3) << 3) | (((cc >> 4) & 1) << 2) | (cc & 3);
    #pragma unroll
    for (int i = 0; i < 16; ++i) {
        int s = i * 4 + rr;
        tile[s][cc] = qkv[(size_t)(b * 2048 + s0 + s) * 3072 + 2048 + h * 64 + cc];
    }
    __syncthreads();
    #pragma unroll
    for (int i = 0; i < 16; ++i) {
        int d = i * 4 + rr;
        vt[(size_t)(bh * 64 + d) * 2048 + s0 + sc] = tile[cc][d];
    }
}

// ===== 2-block/CU double-buffered GEMM (R11/R13/R15-proven core, FROZEN) =====
// OUTF32: 0 = bf16 out, 1 = f32 out | RESID: 0 none, 1 f32 resid, 2 bf16 resid
// GELU: fast tanh-GELU | QSC: scale cols<1024 by (1/8)*log2e (softmax fold)
template<int OUTF32, int RESID, int GELU, int QSC>
__global__ __launch_bounds__(256)
void gemmtlp(const u16* __restrict__ A, const u16* __restrict__ B,
             const float* __restrict__ bias,
             const float* __restrict__ residf, const u16* __restrict__ residb,
             u16* __restrict__ obf, float* __restrict__ of32,
             int M, int N, int K)
{
    constexpr int ABYTES = 128 * 128;      // A tile: 128 rows x 128B = 16KB
    constexpr int BUF = ABYTES * 2;        // + B tile 16KB = 32KB per buffer
    extern __shared__ char lds[];

    const int t = threadIdx.x, lane = t & 63, w = t >> 6;
    const int wr = w >> 1, wc = w & 1, g = lane >> 4, lr = lane & 15;
    const int bm = blockIdx.x * 128, bn = blockIdx.y * 128;

    const int srow = t >> 3;                              // 0..31
    const int scol = (((t & 7) ^ (srow & 7)) * 8);        // pre-swizzled element col
    const u16* ag = A + (size_t)(bm + srow) * K + scol;
    const u16* bg = B + (size_t)(bn + srow) * K + scol;

    f32x4 acc[4][4] = {};

    auto STAGE = [&](int tt) {
        char* bb = lds + (tt & 1) * BUF;
        const size_t ko = (size_t)tt * 64;
        #pragma unroll
        for (int L = 0; L < 4; ++L)
            gload_lds16(ag + (size_t)L * 32 * K + ko, bb + L * 4096 + t * 16);
        #pragma unroll
        for (int L = 0; L < 4; ++L)
            gload_lds16(bg + (size_t)L * 32 * K + ko, bb + ABYTES + L * 4096 + t * 16);
    };

    const int xr = (lr & 7) << 4;          // read-side byte XOR
    const int NT = K >> 6;

    STAGE(0);

    for (int tt = 0; tt < NT; ++tt) {
        VMW0;                               // tile tt landed (issued 1 tile ago)
        __builtin_amdgcn_s_barrier();       // all waves done reading other buffer
        if (tt + 1 < NT) STAGE(tt + 1);     // safe: target buf's readers past barrier

        const char* cbuf = lds + (tt & 1) * BUF;
        s16x8 af[4][2], bf4[4][2];
        #pragma unroll
        for (int mf = 0; mf < 4; ++mf) {
            const int arow = wr * 64 + mf * 16 + lr;
            #pragma unroll
            for (int ks = 0; ks < 2; ++ks)
                af[mf][ks] = *(const s16x8*)(cbuf + arow * 128 + ((ks * 64 + g * 16) ^ xr));
        }
        #pragma unroll
        for (int nf = 0; nf < 4; ++nf) {
            const int brow = wc * 64 + nf * 16 + lr;
            #pragma unroll
            for (int ks = 0; ks < 2; ++ks)
                bf4[nf][ks] = *(const s16x8*)(cbuf + ABYTES + brow * 128 + ((ks * 64 + g * 16) ^ xr));
        }
        __builtin_amdgcn_s_setprio(1);
        #pragma unroll
        for (int ks = 0; ks < 2; ++ks)
            #pragma unroll
            for (int mf = 0; mf < 4; ++mf)
                #pragma unroll
                for (int nf = 0; nf < 4; ++nf)
                    acc[mf][nf] = __builtin_amdgcn_mfma_f32_16x16x32_bf16(
                        af[mf][ks], bf4[nf][ks], acc[mf][nf], 0, 0, 0);
        __builtin_amdgcn_s_setprio(0);
    }

    // epilogue
    #pragma unroll
    for (int mf = 0; mf < 4; ++mf) {
        const int rbase = bm + wr * 64 + mf * 16 + g * 4;
        #pragma unroll
        for (int nf = 0; nf < 4; ++nf) {
            const int col = bn + wc * 64 + nf * 16 + lr;
            const float bia = bias[col];
            #pragma unroll
            for (int b2 = 0; b2 < 4; ++b2) {
                const int r = rbase + b2;
                float v = acc[mf][nf][b2] + bia;
                if (QSC && col < 1024) v *= 0.18033688011112042f;
                if (GELU) v = fgelu(v);
                if (RESID == 1) v += residf[(size_t)r * N + col];
                if (RESID == 2) v += bf2f(residb[(size_t)r * N + col]);
                if (OUTF32) of32[(size_t)r * N + col] = v;
                else        obf[(size_t)r * N + col] = f2bf(v);
            }
        }
    }
}

// ------ flash attention: 128 q-rows/block (8 waves), swapped QK^T, in-register P ------
// KVBLK=128: one barrier per 128 tokens (two 64-token halves, math identical per
// half -> sigma mapping preserved). 16 iterations instead of 32. setprio(1)
// around MFMA clusters (T5, m191: +4-7% on attn).
__global__ __launch_bounds__(512)
void attn_kernel(const u16* __restrict__ qkv, const u16* __restrict__ vt,
                 u16* __restrict__ attnb)
{
    __shared__ u16 Kls[2][8192];   // 128 tokens x 64 d (two 64-token halves)
    __shared__ u16 Vls[2][8192];
    const int t = threadIdx.x, lane = t & 63, w = t >> 6;
    const int g = lane >> 4, lr = lane & 15;
    const int wg = blockIdx.x;
    const int xcd = wg & 7, slot = wg >> 3;        // slot 0..127
    const int bh = xcd * 8 + (slot >> 4);
    const int qt = slot & 15;
    const int b = bh >> 4, h = bh & 15;

    // staging: 512 threads cover one 64x64 tile per gload; 2 passes = 128 tokens
    const int srow = t >> 3;                              // 0..63
    const int scol = (((t & 7) ^ (srow & 7)) * 8);
    const u16* kg = qkv + (size_t)(b * 2048 + srow) * 3072 + 1024 + h * 64 + scol;
    const u16* vg = vt + (size_t)(bh * 64 + srow) * 2048 + scol;

    // stage tile 0 (tokens 0..127)
    gload_lds16(kg, &Kls[0][t * 8]);
    gload_lds16(kg + (size_t)64 * 3072, &Kls[0][4096 + t * 8]);
    gload_lds16(vg, &Vls[0][t * 8]);
    gload_lds16(vg + 64, &Vls[0][4096 + t * 8]);

    const int qtok = b * 2048 + qt * 128 + w * 16 + lr;
    const u16* qp = qkv + (size_t)qtok * 3072 + h * 64;
    const s16x8 qf0 = *(const s16x8*)(qp + g * 8);
    const s16x8 qf1 = *(const s16x8*)(qp + 32 + g * 8);

    f32x4 o[4] = {};
    float psum = 0.f;
    const int xr = (lr & 7) * 8;

    for (int s = 0; s < 16; ++s) {
        const int cur = s & 1;
        __syncthreads();
        if (s + 1 < 16) {
            const size_t ko = (size_t)(s + 1) * 128;
            gload_lds16(kg + ko * 3072, &Kls[cur ^ 1][t * 8]);
            gload_lds16(kg + (ko + 64) * 3072, &Kls[cur ^ 1][4096 + t * 8]);
            gload_lds16(vg + ko, &Vls[cur ^ 1][t * 8]);
            gload_lds16(vg + ko + 64, &Vls[cur ^ 1][4096 + t * 8]);
        }

        #pragma unroll
        for (int hv = 0; hv < 2; ++hv) {           // two 64-token halves
            const u16* Kh = &Kls[cur][hv * 4096];
            const u16* Vh = &Vls[cur][hv * 4096];

            f32x4 sv[4];
            __builtin_amdgcn_s_setprio(1);
            #pragma unroll
            for (int n = 0; n < 4; ++n) {
                const int kr = (n * 16 + lr) * 64;
                const s16x8 k0v = *(const s16x8*)&Kh[kr + ((g * 8) ^ xr)];
                const s16x8 k1v = *(const s16x8*)&Kh[kr + ((32 + g * 8) ^ xr)];
                f32x4 z = {};
                z = __builtin_amdgcn_mfma_f32_16x16x32_bf16(k0v, qf0, z, 0, 0, 0);
                z = __builtin_amdgcn_mfma_f32_16x16x32_bf16(k1v, qf1, z, 0, 0, 0);
                sv[n] = z;
            }
            __builtin_amdgcn_s_setprio(0);

            float p[4][4];
            #pragma unroll
            for (int n = 0; n < 4; ++n) {
                #pragma unroll
                for (int b2 = 0; b2 < 4; ++b2)
                    p[n][b2] = fexp2(sv[n][b2]);
                psum += (p[n][0] + p[n][1]) + (p[n][2] + p[n][3]);
            }

            u32x4 pk0, pk1;
            pk0[0] = cvt_pk_bf16(p[0][0], p[0][1]);
            pk0[1] = cvt_pk_bf16(p[0][2], p[0][3]);
            pk0[2] = cvt_pk_bf16(p[1][0], p[1][1]);
            pk0[3] = cvt_pk_bf16(p[1][2], p[1][3]);
            pk1[0] = cvt_pk_bf16(p[2][0], p[2][1]);
            pk1[1] = cvt_pk_bf16(p[2][2], p[2][3]);
            pk1[2] = cvt_pk_bf16(p[3][0], p[3][1]);
            pk1[3] = cvt_pk_bf16(p[3][2], p[3][3]);
            const s16x8 pa0 = __builtin_bit_cast(s16x8, pk0);
            const s16x8 pa1 = __builtin_bit_cast(s16x8, pk1);

            __builtin_amdgcn_s_setprio(1);
            #pragma unroll
            for (int n = 0; n < 4; ++n) {
                const int vr = (n * 16 + lr) * 64;
                const s16x8 v0 = *(const s16x8*)&Vh[vr + ((g * 8) ^ xr)];
                const s16x8 v1 = *(const s16x8*)&Vh[vr + ((32 + g * 8) ^ xr)];
                o[n] = __builtin_amdgcn_mfma_f32_16x16x32_bf16(pa0, v0, o[n], 0, 0, 0);
                o[n] = __builtin_amdgcn_mfma_f32_16x16x32_bf16(pa1, v1, o[n], 0, 0, 0);
            }
            __builtin_amdgcn_s_setprio(0);
        }
    }

    psum += __shfl_xor(psum, 16);
    psum += __shfl_xor(psum, 32);
    const int orow0 = b * 2048 + qt * 128 + w * 16 + g * 4;
    #pragma unroll
    for (int b2 = 0; b2 < 4; ++b2) {
        const float inv = frcp(__shfl(psum, g * 4 + b2));
        #pragma unroll
        for (int n = 0; n < 4; ++n)
            attnb[(size_t)(orow0 + b2) * 1024 + h * 64 + n * 16 + lr] = f2bf(o[n][b2] * inv);
    }
}

// ---------------- LayerNorm: bf16 in -> bf16 out ----------------
__global__ __launch_bounds__(256)
void ln_kernel(const u16* __restrict__ x, const float* __restrict__ lw,
               const float* __restrict__ lb, u16* __restrict__ out)
{
    const int row = blockIdx.x;
    const int t = threadIdx.x;
    const ushort4 xv = ((const ushort4*)(x + (size_t)row * 1024))[t];
    const float v0 = bf2f(xv.x), v1 = bf2f(xv.y), v2 = bf2f(xv.z), v3 = bf2f(xv.w);
    float s = v0 + v1 + v2 + v3;
    float s2 = v0 * v0 + v1 * v1 + v2 * v2 + v3 * v3;
    #pragma unroll
    for (int m = 32; m >= 1; m >>= 1) {
        s  += __shfl_xor(s, m);
        s2 += __shfl_xor(s2, m);
    }
    __shared__ float red[16];
    const int w = t >> 6, lane = t & 63;
    if (lane == 0) { red[w] = s; red[8 + w] = s2; }
    __syncthreads();
    s  = red[0] + red[1] + red[2] + red[3];
    s2 = red[8] + red[9] + red[10] + red[11];
    const float mu = s * (1.0f / 1024.0f);
    const float var = s2 * (1.0f / 1024.0f) - mu * mu;
    const float inv = rsqrtf(var + 1e-5f);
    const float4 wv = ((const float4*)lw)[t];
    const float4 bv = ((const float4*)lb)[t];
    ushort4 oo;
    oo.x = f2bf((v0 - mu) * inv * wv.x + bv.x);
    oo.y = f2bf((v1 - mu) * inv * wv.y + bv.y);
    oo.z = f2bf((v2 - mu) * inv * wv.z + bv.z);
    oo.w = f2bf((v3 - mu) * inv * wv.w + bv.w);
    ((ushort4*)(out + (size_t)row * 1024))[t] = oo;
}

extern "C" void kernel_launch(void* const* d_in, const int* in_sizes, int n_in,
                              void* d_out, int out_size, void* d_ws, size_t ws_size,
                              hipStream_t stream)
{
    const float* x      = (const float*)d_in[0];
    const float* w_attn = (const float*)d_in[1];
    const float* b_attn = (const float*)d_in[2];
    const float* w_o    = (const float*)d_in[3];
    const float* b_o    = (const float*)d_in[4];
    const float* ln_w   = (const float*)d_in[5];
    const float* ln_b   = (const float*)d_in[6];
    const float* w_fc1  = (const float*)d_in[7];
    const float* b_fc1  = (const float*)d_in[8];
    const float* w_fc2  = (const float*)d_in[9];
    const float* b_fc2  = (const float*)d_in[10];
    float* out = (float*)d_out;

    char* ws = (char*)d_ws;
    u16*   xb    = (u16*)(ws);                       // 16 MB  bf16 x
    u16*   wqkvT = (u16*)(ws + 16777216);            //  6 MB  [3072][1024]
    u16*   woT   = (u16*)(ws + 23068672);            //  2 MB  [1024][1024]
    u16*   w1T   = (u16*)(ws + 25165824);            //  8 MB  [4096][1024]
    u16*   w2T   = (u16*)(ws + 33554432);            //  8 MB  [1024][4096]
    u16*   x1b   = (u16*)(ws + 41943040);            // 16 MB  bf16 residual-1
    u16*   attnb = (u16*)(ws + 75497472);            // 16 MB  (later reused as hb)
    u16*   hb    = attnb;
    u16*   qkvb  = (u16*)(ws + 92274688);            // 48 MB  [8192][3072]
    u16*   vtb   = qkvb + 25165824;                  // 16 MB  [64][64][2048]
    u16*   h1    = qkvb;                             // 64 MB alias (qkv+vt dead after attn)

    cvt_bf16_kernel<<<2048, 256, 0, stream>>>(x, xb, 8192 * 1024 / 4);
    transpose_cvt<<<dim3(48, 16), 256, 0, stream>>>(w_attn, wqkvT, 1024, 3072);
    transpose_cvt<<<dim3(16, 16), 256, 0, stream>>>(w_o,   woT,  1024, 1024);
    transpose_cvt<<<dim3(64, 16), 256, 0, stream>>>(w_fc1, w1T,  1024, 4096);
    transpose_cvt<<<dim3(16, 64), 256, 0, stream>>>(w_fc2, w2T,  4096, 1024);

    // qkv = x @ w_attn + b_attn   [Q cols pre-scaled; LDS 64KB -> 2 blocks/CU]
    gemmtlp<0, 0, 0, 1><<<dim3(64, 24), 256, 65536, stream>>>(
        xb, wqkvT, b_attn, nullptr, nullptr, qkvb, nullptr, 8192, 3072, 1024);
    vtrans_kernel<<<dim3(32, 64), 256, 0, stream>>>(qkvb, vtb);
    attn_kernel<<<1024, 512, 0, stream>>>(qkvb, vtb, attnb);
    // x1b = bf16(attn @ w_o + b_o + x)   [resid = f32 x]
    gemmtlp<0, 1, 0, 0><<<dim3(64, 8), 256, 65536, stream>>>(
        attnb, woT, b_o, x, nullptr, x1b, nullptr, 8192, 1024, 1024);
    ln_kernel<<<8192, 256, 0, stream>>>(x1b, ln_w, ln_b, hb);
    // h1 = gelu(h @ w_fc1 + b_fc1)   [fast tanh-GELU]
    gemmtlp<0, 0, 1, 0><<<dim3(64, 32), 256, 65536, stream>>>(
        hb, w1T, b_fc1, nullptr, nullptr, h1, nullptr, 8192, 4096, 1024);
    // out = h1 @ w_fc2 + b_fc2 + x1b   [f32 out, bf16 resid, K=4096]
    gemmtlp<1, 2, 0, 0><<<dim3(64, 8), 256, 65536, stream>>>(
        h1, w2T, b_fc2, nullptr, x1b, nullptr, out, 8192, 1024, 4096);
}

// Round 17
// 350.176 us; speedup vs baseline: 1.0120x; 1.0120x over previous
//
#include <hip/hip_runtime.h>
#include <hip/hip_bf16.h>
#include <math.h>
#include <stdint.h>

typedef __attribute__((ext_vector_type(8))) short s16x8;
typedef __attribute__((ext_vector_type(4))) float f32x4;
typedef __attribute__((ext_vector_type(4))) u_int32_t u32x4;
typedef unsigned int u32;
typedef unsigned short u16;

#define DEVINL __device__ __forceinline__
#define VMW0 asm volatile("s_waitcnt vmcnt(0)" ::: "memory")

DEVINL u16 f2bf(float f) {
    u32 b = __builtin_bit_cast(u32, f);
    u32 r = (b + 0x7fffu + ((b >> 16) & 1u)) >> 16;
    return (u16)r;
}

DEVINL float bf2f(u16 u) {
    u32 b = (u32)u << 16;
    return __builtin_bit_cast(float, b);
}

DEVINL float fexp2(float x) {
    float r;
    asm("v_exp_f32 %0, %1" : "=v"(r) : "v"(x));
    return r;
}

DEVINL float frcp(float x) {
    float r;
    asm("v_rcp_f32 %0, %1" : "=v"(r) : "v"(x));
    return r;
}

DEVINL u32 cvt_pk_bf16(float lo, float hi) {
    u32 r;
    asm("v_cvt_pk_bf16_f32 %0, %1, %2" : "=v"(r) : "v"(lo), "v"(hi));
    return r;
}

// fast GELU: tanh form, gelu(x) = x*u/(u+1), u = exp2(x*(c1 + c2*x^2))
DEVINL float fgelu(float v) {
    const float x2 = v * v;
    const float u = fexp2(v * __builtin_fmaf(0.10294310f, x2, 2.3022165f));
    return v * u * frcp(u + 1.0f);
}

DEVINL void gload_lds16(const void* g, const void* l) {
    __builtin_amdgcn_global_load_lds(
        (const __attribute__((address_space(1))) u32*)(uintptr_t)g,
        (__attribute__((address_space(3))) u32*)(uintptr_t)l, 16, 0, 0);
}

// ---------------- elementwise f32 -> bf16 ----------------
__global__ __launch_bounds__(256)
void cvt_bf16_kernel(const float* __restrict__ in, u16* __restrict__ out, int n4)
{
    int i = blockIdx.x * 256 + threadIdx.x;
    const int stride = gridDim.x * 256;
    for (; i < n4; i += stride) {
        float4 v = ((const float4*)in)[i];
        ushort4 o;
        o.x = f2bf(v.x); o.y = f2bf(v.y); o.z = f2bf(v.z); o.w = f2bf(v.w);
        ((ushort4*)out)[i] = o;
    }
}

// ------------- transpose + convert weights: src[R][C] f32 -> dst[C][R] bf16 -------------
__global__ __launch_bounds__(256)
void transpose_cvt(const float* __restrict__ src, u16* __restrict__ dst, int R, int C)
{
    __shared__ float tile[64][65];
    const int t = threadIdx.x;
    const int c0 = blockIdx.x * 64, r0 = blockIdx.y * 64;
    const int rr = t >> 6;   // 0..3
    const int cc = t & 63;
    #pragma unroll
    for (int i = 0; i < 16; ++i)
        tile[i * 4 + rr][cc] = src[(size_t)(r0 + i * 4 + rr) * C + c0 + cc];
    __syncthreads();
    #pragma unroll
    for (int i = 0; i < 16; ++i) {
        int orow = i * 4 + rr;           // source col
        dst[(size_t)(c0 + orow) * R + r0 + cc] = f2bf(tile[cc][orow]);
    }
}

// ------------- V transpose: qkv[B,T, 2048+h*64+d] bf16 -> vt[bh, d, sigma(t)] bf16 -------
// sigma: token cc stored at position matching the in-register packed-P virtual k-order
__global__ __launch_bounds__(256)
void vtrans_kernel(const u16* __restrict__ qkv, u16* __restrict__ vt)
{
    __shared__ u16 tile[64][68];
    const int t = threadIdx.x;
    const int st = blockIdx.x;       // T/64
    const int bh = blockIdx.y;       // B*H
    const int b = bh >> 4, h = bh & 15;
    const int s0 = st * 64;
    const int rr = t >> 6, cc = t & 63;
    const int sc = (cc & 32) | (((cc >> 2) & 3) << 3) | (((cc >> 4) & 1) << 2) | (cc & 3);
    #pragma unroll
    for (int i = 0; i < 16; ++i) {
        int s = i * 4 + rr;
        tile[s][cc] = qkv[(size_t)(b * 2048 + s0 + s) * 3072 + 2048 + h * 64 + cc];
    }
    __syncthreads();
    #pragma unroll
    for (int i = 0; i < 16; ++i) {
        int d = i * 4 + rr;
        vt[(size_t)(bh * 64 + d) * 2048 + s0 + sc] = tile[cc][d];
    }
}

// ===== 2-block/CU double-buffered GEMM (R11/R13/R15-proven core, FROZEN) =====
// OUTF32: 0 = bf16 out, 1 = f32 out | RESID: 0 none, 1 f32 resid, 2 bf16 resid
// GELU: fast tanh-GELU | QSC: scale cols<1024 by (1/8)*log2e (softmax fold)
template<int OUTF32, int RESID, int GELU, int QSC>
__global__ __launch_bounds__(256)
void gemmtlp(const u16* __restrict__ A, const u16* __restrict__ B,
             const float* __restrict__ bias,
             const float* __restrict__ residf, const u16* __restrict__ residb,
             u16* __restrict__ obf, float* __restrict__ of32,
             int M, int N, int K)
{
    constexpr int ABYTES = 128 * 128;      // A tile: 128 rows x 128B = 16KB
    constexpr int BUF = ABYTES * 2;        // + B tile 16KB = 32KB per buffer
    extern __shared__ char lds[];

    const int t = threadIdx.x, lane = t & 63, w = t >> 6;
    const int wr = w >> 1, wc = w & 1, g = lane >> 4, lr = lane & 15;
    const int bm = blockIdx.x * 128, bn = blockIdx.y * 128;

    const int srow = t >> 3;                              // 0..31
    const int scol = (((t & 7) ^ (srow & 7)) * 8);        // pre-swizzled element col
    const u16* ag = A + (size_t)(bm + srow) * K + scol;
    const u16* bg = B + (size_t)(bn + srow) * K + scol;

    f32x4 acc[4][4] = {};

    auto STAGE = [&](int tt) {
        char* bb = lds + (tt & 1) * BUF;
        const size_t ko = (size_t)tt * 64;
        #pragma unroll
        for (int L = 0; L < 4; ++L)
            gload_lds16(ag + (size_t)L * 32 * K + ko, bb + L * 4096 + t * 16);
        #pragma unroll
        for (int L = 0; L < 4; ++L)
            gload_lds16(bg + (size_t)L * 32 * K + ko, bb + ABYTES + L * 4096 + t * 16);
    };

    const int xr = (lr & 7) << 4;          // read-side byte XOR
    const int NT = K >> 6;

    STAGE(0);

    for (int tt = 0; tt < NT; ++tt) {
        VMW0;                               // tile tt landed (issued 1 tile ago)
        __builtin_amdgcn_s_barrier();       // all waves done reading other buffer
        if (tt + 1 < NT) STAGE(tt + 1);     // safe: target buf's readers past barrier

        const char* cbuf = lds + (tt & 1) * BUF;
        s16x8 af[4][2], bf4[4][2];
        #pragma unroll
        for (int mf = 0; mf < 4; ++mf) {
            const int arow = wr * 64 + mf * 16 + lr;
            #pragma unroll
            for (int ks = 0; ks < 2; ++ks)
                af[mf][ks] = *(const s16x8*)(cbuf + arow * 128 + ((ks * 64 + g * 16) ^ xr));
        }
        #pragma unroll
        for (int nf = 0; nf < 4; ++nf) {
            const int brow = wc * 64 + nf * 16 + lr;
            #pragma unroll
            for (int ks = 0; ks < 2; ++ks)
                bf4[nf][ks] = *(const s16x8*)(cbuf + ABYTES + brow * 128 + ((ks * 64 + g * 16) ^ xr));
        }
        __builtin_amdgcn_s_setprio(1);
        #pragma unroll
        for (int ks = 0; ks < 2; ++ks)
            #pragma unroll
            for (int mf = 0; mf < 4; ++mf)
                #pragma unroll
                for (int nf = 0; nf < 4; ++nf)
                    acc[mf][nf] = __builtin_amdgcn_mfma_f32_16x16x32_bf16(
                        af[mf][ks], bf4[nf][ks], acc[mf][nf], 0, 0, 0);
        __builtin_amdgcn_s_setprio(0);
    }

    // epilogue
    #pragma unroll
    for (int mf = 0; mf < 4; ++mf) {
        const int rbase = bm + wr * 64 + mf * 16 + g * 4;
        #pragma unroll
        for (int nf = 0; nf < 4; ++nf) {
            const int col = bn + wc * 64 + nf * 16 + lr;
            const float bia = bias[col];
            #pragma unroll
            for (int b2 = 0; b2 < 4; ++b2) {
                const int r = rbase + b2;
                float v = acc[mf][nf][b2] + bia;
                if (QSC && col < 1024) v *= 0.18033688011112042f;
                if (GELU) v = fgelu(v);
                if (RESID == 1) v += residf[(size_t)r * N + col];
                if (RESID == 2) v += bf2f(residb[(size_t)r * N + col]);
                if (OUTF32) of32[(size_t)r * N + col] = v;
                else        obf[(size_t)r * N + col] = f2bf(v);
            }
        }
    }
}

// ------ flash attention (R15-proven): 128 q-rows/block (8 waves), swapped QK^T ------
// KVBLK=64, double-buffered, XOR-swizzled; in-register P via cvt_pk; max-free exp2.
__global__ __launch_bounds__(512)
void attn_kernel(const u16* __restrict__ qkv, const u16* __restrict__ vt,
                 u16* __restrict__ attnb)
{
    __shared__ u16 Kls[2][4096];
    __shared__ u16 Vls[2][4096];
    const int t = threadIdx.x, lane = t & 63, w = t >> 6;
    const int g = lane >> 4, lr = lane & 15;
    const int wg = blockIdx.x;
    const int xcd = wg & 7, slot = wg >> 3;        // slot 0..127
    const int bh = xcd * 8 + (slot >> 4);
    const int qt = slot & 15;
    const int b = bh >> 4, h = bh & 15;

    const int srow = t >> 3;                              // 0..63
    const int scol = (((t & 7) ^ (srow & 7)) * 8);
    const u16* kg = qkv + (size_t)(b * 2048 + srow) * 3072 + 1024 + h * 64 + scol;
    const u16* vg = vt + (size_t)(bh * 64 + srow) * 2048 + scol;

    gload_lds16(kg, &Kls[0][t * 8]);
    gload_lds16(vg, &Vls[0][t * 8]);

    const int qtok = b * 2048 + qt * 128 + w * 16 + lr;
    const u16* qp = qkv + (size_t)qtok * 3072 + h * 64;
    const s16x8 qf0 = *(const s16x8*)(qp + g * 8);
    const s16x8 qf1 = *(const s16x8*)(qp + 32 + g * 8);

    f32x4 o[4] = {};
    float psum = 0.f;
    const int xr = (lr & 7) * 8;

    for (int s = 0; s < 32; ++s) {
        const int cur = s & 1;
        __syncthreads();
        if (s + 1 < 32) {
            const size_t ko = (size_t)(s + 1) * 64;
            gload_lds16(kg + ko * 3072, &Kls[cur ^ 1][t * 8]);
            gload_lds16(vg + ko, &Vls[cur ^ 1][t * 8]);
        }

        f32x4 sv[4];
        #pragma unroll
        for (int n = 0; n < 4; ++n) {
            const int kr = (n * 16 + lr) * 64;
            const s16x8 k0v = *(const s16x8*)&Kls[cur][kr + ((g * 8) ^ xr)];
            const s16x8 k1v = *(const s16x8*)&Kls[cur][kr + ((32 + g * 8) ^ xr)];
            f32x4 z = {};
            z = __builtin_amdgcn_mfma_f32_16x16x32_bf16(k0v, qf0, z, 0, 0, 0);
            z = __builtin_amdgcn_mfma_f32_16x16x32_bf16(k1v, qf1, z, 0, 0, 0);
            sv[n] = z;
        }

        float p[4][4];
        #pragma unroll
        for (int n = 0; n < 4; ++n) {
            #pragma unroll
            for (int b2 = 0; b2 < 4; ++b2)
                p[n][b2] = fexp2(sv[n][b2]);
            psum += (p[n][0] + p[n][1]) + (p[n][2] + p[n][3]);
        }

        u32x4 pk0, pk1;
        pk0[0] = cvt_pk_bf16(p[0][0], p[0][1]);
        pk0[1] = cvt_pk_bf16(p[0][2], p[0][3]);
        pk0[2] = cvt_pk_bf16(p[1][0], p[1][1]);
        pk0[3] = cvt_pk_bf16(p[1][2], p[1][3]);
        pk1[0] = cvt_pk_bf16(p[2][0], p[2][1]);
        pk1[1] = cvt_pk_bf16(p[2][2], p[2][3]);
        pk1[2] = cvt_pk_bf16(p[3][0], p[3][1]);
        pk1[3] = cvt_pk_bf16(p[3][2], p[3][3]);
        const s16x8 pa0 = __builtin_bit_cast(s16x8, pk0);
        const s16x8 pa1 = __builtin_bit_cast(s16x8, pk1);

        #pragma unroll
        for (int n = 0; n < 4; ++n) {
            const int vr = (n * 16 + lr) * 64;
            const s16x8 v0 = *(const s16x8*)&Vls[cur][vr + ((g * 8) ^ xr)];
            const s16x8 v1 = *(const s16x8*)&Vls[cur][vr + ((32 + g * 8) ^ xr)];
            o[n] = __builtin_amdgcn_mfma_f32_16x16x32_bf16(pa0, v0, o[n], 0, 0, 0);
            o[n] = __builtin_amdgcn_mfma_f32_16x16x32_bf16(pa1, v1, o[n], 0, 0, 0);
        }
    }

    psum += __shfl_xor(psum, 16);
    psum += __shfl_xor(psum, 32);
    const int orow0 = b * 2048 + qt * 128 + w * 16 + g * 4;
    #pragma unroll
    for (int b2 = 0; b2 < 4; ++b2) {
        const float inv = frcp(__shfl(psum, g * 4 + b2));
        #pragma unroll
        for (int n = 0; n < 4; ++n)
            attnb[(size_t)(orow0 + b2) * 1024 + h * 64 + n * 16 + lr] = f2bf(o[n][b2] * inv);
    }
}

// ---------------- LayerNorm: bf16 in -> bf16 out ----------------
__global__ __launch_bounds__(256)
void ln_kernel(const u16* __restrict__ x, const float* __restrict__ lw,
               const float* __restrict__ lb, u16* __restrict__ out)
{
    const int row = blockIdx.x;
    const int t = threadIdx.x;
    const ushort4 xv = ((const ushort4*)(x + (size_t)row * 1024))[t];
    const float v0 = bf2f(xv.x), v1 = bf2f(xv.y), v2 = bf2f(xv.z), v3 = bf2f(xv.w);
    float s = v0 + v1 + v2 + v3;
    float s2 = v0 * v0 + v1 * v1 + v2 * v2 + v3 * v3;
    #pragma unroll
    for (int m = 32; m >= 1; m >>= 1) {
        s  += __shfl_xor(s, m);
        s2 += __shfl_xor(s2, m);
    }
    __shared__ float red[16];
    const int w = t >> 6, lane = t & 63;
    if (lane == 0) { red[w] = s; red[8 + w] = s2; }
    __syncthreads();
    s  = red[0] + red[1] + red[2] + red[3];
    s2 = red[8] + red[9] + red[10] + red[11];
    const float mu = s * (1.0f / 1024.0f);
    const float var = s2 * (1.0f / 1024.0f) - mu * mu;
    const float inv = rsqrtf(var + 1e-5f);
    const float4 wv = ((const float4*)lw)[t];
    const float4 bv = ((const float4*)lb)[t];
    ushort4 oo;
    oo.x = f2bf((v0 - mu) * inv * wv.x + bv.x);
    oo.y = f2bf((v1 - mu) * inv * wv.y + bv.y);
    oo.z = f2bf((v2 - mu) * inv * wv.z + bv.z);
    oo.w = f2bf((v3 - mu) * inv * wv.w + bv.w);
    ((ushort4*)(out + (size_t)row * 1024))[t] = oo;
}

extern "C" void kernel_launch(void* const* d_in, const int* in_sizes, int n_in,
                              void* d_out, int out_size, void* d_ws, size_t ws_size,
                              hipStream_t stream)
{
    const float* x      = (const float*)d_in[0];
    const float* w_attn = (const float*)d_in[1];
    const float* b_attn = (const float*)d_in[2];
    const float* w_o    = (const float*)d_in[3];
    const float* b_o    = (const float*)d_in[4];
    const float* ln_w   = (const float*)d_in[5];
    const float* ln_b   = (const float*)d_in[6];
    const float* w_fc1  = (const float*)d_in[7];
    const float* b_fc1  = (const float*)d_in[8];
    const float* w_fc2  = (const float*)d_in[9];
    const float* b_fc2  = (const float*)d_in[10];
    float* out = (float*)d_out;

    char* ws = (char*)d_ws;
    u16*   xb    = (u16*)(ws);                       // 16 MB  bf16 x
    u16*   wqkvT = (u16*)(ws + 16777216);            //  6 MB  [3072][1024]
    u16*   woT   = (u16*)(ws + 23068672);            //  2 MB  [1024][1024]
    u16*   w1T   = (u16*)(ws + 25165824);            //  8 MB  [4096][1024]
    u16*   w2T   = (u16*)(ws + 33554432);            //  8 MB  [1024][4096]
    u16*   x1b   = (u16*)(ws + 41943040);            // 16 MB  bf16 residual-1
    u16*   attnb = (u16*)(ws + 75497472);            // 16 MB  (later reused as hb)
    u16*   hb    = attnb;
    u16*   qkvb  = (u16*)(ws + 92274688);            // 48 MB  [8192][3072]
    u16*   vtb   = qkvb + 25165824;                  // 16 MB  [64][64][2048]
    u16*   h1    = qkvb;                             // 64 MB alias (qkv+vt dead after attn)

    cvt_bf16_kernel<<<2048, 256, 0, stream>>>(x, xb, 8192 * 1024 / 4);
    transpose_cvt<<<dim3(48, 16), 256, 0, stream>>>(w_attn, wqkvT, 1024, 3072);
    transpose_cvt<<<dim3(16, 16), 256, 0, stream>>>(w_o,   woT,  1024, 1024);
    transpose_cvt<<<dim3(64, 16), 256, 0, stream>>>(w_fc1, w1T,  1024, 4096);
    transpose_cvt<<<dim3(16, 64), 256, 0, stream>>>(w_fc2, w2T,  4096, 1024);

    // qkv = x @ w_attn + b_attn   [Q cols pre-scaled; LDS 64KB -> 2 blocks/CU]
    gemmtlp<0, 0, 0, 1><<<dim3(64, 24), 256, 65536, stream>>>(
        xb, wqkvT, b_attn, nullptr, nullptr, qkvb, nullptr, 8192, 3072, 1024);
    vtrans_kernel<<<dim3(32, 64), 256, 0, stream>>>(qkvb, vtb);
    attn_kernel<<<1024, 512, 0, stream>>>(qkvb, vtb, attnb);
    // x1b = bf16(attn @ w_o + b_o + xb)   [resid = bf16 xb: halves resid read traffic]
    gemmtlp<0, 2, 0, 0><<<dim3(64, 8), 256, 65536, stream>>>(
        attnb, woT, b_o, nullptr, xb, x1b, nullptr, 8192, 1024, 1024);
    ln_kernel<<<8192, 256, 0, stream>>>(x1b, ln_w, ln_b, hb);
    // h1 = gelu(h @ w_fc1 + b_fc1)   [fast tanh-GELU]
    gemmtlp<0, 0, 1, 0><<<dim3(64, 32), 256, 65536, stream>>>(
        hb, w1T, b_fc1, nullptr, nullptr, h1, nullptr, 8192, 4096, 1024);
    // out = h1 @ w_fc2 + b_fc2 + x1b   [f32 out, bf16 resid, K=4096]
    gemmtlp<1, 2, 0, 0><<<dim3(64, 8), 256, 65536, stream>>>(
        h1, w2T, b_fc2, nullptr, x1b, nullptr, out, 8192, 1024, 4096);
}